// Round 2
// baseline (899.013 us; speedup 1.0000x reference)
//
#include <hip/hip_runtime.h>

// GreedyGroupedRouter: softmax(524288x256) + grouped top-1-of-32 (8 groups)
// + normalized topk weights + 256-bin histogram.
//
// Output layout in d_out (all float32, concatenated flat):
//   [0)                    routing_weights : SEQ*256
//   [SEQ*256)              topk_weights    : SEQ*8
//   [SEQ*256 + SEQ*8)      topk_ids        : SEQ*8  (integer values as float)
//   [SEQ*256 + 2*SEQ*8)    tokens_per_expert : 256

#define SEQ_N    524288
#define NEXP     256
#define NGROUP   8
#define GSIZE    32
#define TOPK     8

__global__ void zero_hist_kernel(float* __restrict__ tokens) {
    // 256 threads, one element each
    tokens[threadIdx.x] = 0.0f;
}

__global__ __launch_bounds__(256, 8) void router_kernel(
    const float* __restrict__ logits,
    float* __restrict__ routing_weights,
    float* __restrict__ topk_weights,
    float* __restrict__ topk_ids,
    float* __restrict__ tokens_per_expert)
{
    __shared__ int hist[NEXP];
    const int t = threadIdx.x;
    if (t < NEXP) hist[t] = 0;
    __syncthreads();

    const int lane = t & 63;
    const int waves_in_grid = (gridDim.x * blockDim.x) >> 6;
    const int wave_id = (blockIdx.x * blockDim.x + t) >> 6;

    for (int row = wave_id; row < SEQ_N; row += waves_in_grid) {
        const size_t base = (size_t)row * NEXP + (size_t)lane * 4;
        const float4 v = *reinterpret_cast<const float4*>(logits + base);

        // ---- row max (64-lane butterfly) ----
        float mm = fmaxf(fmaxf(v.x, v.y), fmaxf(v.z, v.w));
        #pragma unroll
        for (int s = 32; s >= 1; s >>= 1) mm = fmaxf(mm, __shfl_xor(mm, s));

        // ---- exp + row sum ----
        const float e0 = __expf(v.x - mm);
        const float e1 = __expf(v.y - mm);
        const float e2 = __expf(v.z - mm);
        const float e3 = __expf(v.w - mm);
        float ssum = (e0 + e1) + (e2 + e3);
        #pragma unroll
        for (int s = 32; s >= 1; s >>= 1) ssum += __shfl_xor(ssum, s);
        const float inv = 1.0f / ssum;

        // ---- write softmax row (coalesced float4) ----
        float4 w;
        w.x = e0 * inv; w.y = e1 * inv; w.z = e2 * inv; w.w = e3 * inv;
        *reinterpret_cast<float4*>(routing_weights + base) = w;

        // ---- per-lane argmax over its 4 logits (prefer smaller index) ----
        float bv = v.x; int bi = lane * 4;
        if (v.y > bv) { bv = v.y; bi = lane * 4 + 1; }
        if (v.z > bv) { bv = v.z; bi = lane * 4 + 2; }
        if (v.w > bv) { bv = v.w; bi = lane * 4 + 3; }

        // ---- group argmax across the 8 lanes of this group (xor 4,2,1) ----
        #pragma unroll
        for (int s = 4; s >= 1; s >>= 1) {
            const float ov = __shfl_xor(bv, s);
            const int   oi = __shfl_xor(bi, s);
            if (ov > bv || (ov == bv && oi < bi)) { bv = ov; bi = oi; }
        }
        // all 8 lanes of a group now hold (group max logit, global expert id)

        // selected softmax weight for this group (identical across the group)
        const float selw = __expf(bv - mm) * inv;

        // ---- sum of the 8 selected weights (one rep lane per group) ----
        float tot = ((lane & 7) == 0) ? selw : 0.0f;
        #pragma unroll
        for (int s = 32; s >= 1; s >>= 1) tot += __shfl_xor(tot, s);

        const float normw = selw / (tot + 1e-20f);

        if ((lane & 7) == 0) {
            const int g = lane >> 3;
            const size_t o = (size_t)row * TOPK + g;
            topk_weights[o] = normw;
            topk_ids[o]     = (float)bi;   // exact int value as float
            atomicAdd(&hist[bi], 1);
        }
    }

    __syncthreads();
    if (t < NEXP) {
        const int c = hist[t];
        if (c) atomicAdd(&tokens_per_expert[t], (float)c);
    }
}

extern "C" void kernel_launch(void* const* d_in, const int* in_sizes, int n_in,
                              void* d_out, int out_size, void* d_ws, size_t ws_size,
                              hipStream_t stream) {
    const float* logits = (const float*)d_in[0];
    float* out = (float*)d_out;

    float* routing_weights   = out;
    float* topk_weights      = out + (size_t)SEQ_N * NEXP;
    float* topk_ids          = out + (size_t)SEQ_N * NEXP + (size_t)SEQ_N * TOPK;
    float* tokens_per_expert = out + (size_t)SEQ_N * NEXP + 2ull * SEQ_N * TOPK;

    // zero the histogram bins (d_out is poisoned before every timed launch)
    zero_hist_kernel<<<1, NEXP, 0, stream>>>(tokens_per_expert);

    // 2048 blocks x 256 threads = 8192 waves; 64 rows per wave (grid-stride)
    router_kernel<<<2048, 256, 0, stream>>>(
        logits, routing_weights, topk_weights, topk_ids, tokens_per_expert);
}